// Round 1
// baseline (610.957 us; speedup 1.0000x reference)
//
#include <hip/hip_runtime.h>

// Problem constants
#define B_  64
#define C_  3
#define H_  512
#define W_  512
#define OC_ 16
#define OH_ 510
#define OW_ 510

// Tile geometry: each 256-thread block computes a 64(x) x 16(y) output tile.
#define TX_ 64
#define TY_ 16
#define TILES_X_ 8    // ceil(510/64)
#define TILES_Y_ 32   // ceil(510/16)
#define SMW_ 66       // TX+2
#define SMH_ 18       // TY+2

// NaN-safe tanh: 1 - 2/(e^{2x}+1). For 2x overflow e=inf -> 1-0 = 1 (no inf/inf).
__device__ __forceinline__ float fast_tanh(float v) {
    float e = __expf(2.0f * v);
    return 1.0f - 2.0f * __builtin_amdgcn_rcpf(e + 1.0f);
}

__global__ __launch_bounds__(256)
void conv3x3_min_tanh(const float* __restrict__ x, const float* __restrict__ wgt,
                      const float* __restrict__ bias, float* __restrict__ out) {
    __shared__ float smem[C_ * SMH_ * SMW_];   // 3*18*66*4 = 14.3 KB

    const int blk = blockIdx.x;
    const int bx = blk % TILES_X_;
    const int by = (blk / TILES_X_) % TILES_Y_;
    const int b  = blk / (TILES_X_ * TILES_Y_);
    const int ox0 = bx * TX_;
    const int oy0 = by * TY_;

    // ---- stage input tile (clamped at borders; clamped values never stored) ----
    const float* xb = x + (size_t)b * C_ * H_ * W_;
    constexpr int NSTAGE = C_ * SMH_ * SMW_;   // 3564
    for (int i = threadIdx.x; i < NSTAGE; i += 256) {
        int c  = i / (SMH_ * SMW_);
        int r  = (i % (SMH_ * SMW_)) / SMW_;
        int xx = i % SMW_;
        int gy = min(oy0 + r,  H_ - 1);
        int gx = min(ox0 + xx, W_ - 1);
        smem[i] = xb[(c * H_ + gy) * W_ + gx];
    }
    __syncthreads();

    // ---- compute: each thread owns x = ox0+lx, y = oy0 + tyg*4 + p (p=0..3) ----
    const int lx  = threadIdx.x & 63;
    const int tyg = threadIdx.x >> 6;   // 0..3

    float acc[OC_][4];
    #pragma unroll
    for (int o = 0; o < OC_; ++o) {
        float bv = bias[o];               // wave-uniform scalar load
        #pragma unroll
        for (int p = 0; p < 4; ++p) acc[o][p] = bv;
    }

    #pragma unroll
    for (int c = 0; c < C_; ++c) {
        // 6 rows x 3 cols of input cover all (p,ky) combos for this channel
        float iv[6][3];
        #pragma unroll
        for (int r = 0; r < 6; ++r)
            #pragma unroll
            for (int k = 0; k < 3; ++k)
                iv[r][k] = smem[(c * SMH_ + tyg * 4 + r) * SMW_ + lx + k];

        #pragma unroll
        for (int o = 0; o < OC_; ++o)
            #pragma unroll
            for (int ky = 0; ky < 3; ++ky)
                #pragma unroll
                for (int kx = 0; kx < 3; ++kx) {
                    // wave-uniform weight -> SGPR operand of v_fma_f32
                    float wv = wgt[((o * C_ + c) * 3 + ky) * 3 + kx];
                    #pragma unroll
                    for (int p = 0; p < 4; ++p)
                        acc[o][p] = fmaf(wv, iv[p + ky][kx], acc[o][p]);
                }
    }

    // ---- epilogue: channel-min, double tanh, coalesced store ----
    #pragma unroll
    for (int p = 0; p < 4; ++p) {
        float m = acc[0][p];
        #pragma unroll
        for (int o = 1; o < OC_; ++o) m = fminf(m, acc[o][p]);
        float t = fast_tanh(fast_tanh(m));
        int oy = oy0 + tyg * 4 + p;
        int ox = ox0 + lx;
        if (oy < OH_ && ox < OW_)
            out[((size_t)b * OH_ + oy) * OW_ + ox] = t;
    }
}

extern "C" void kernel_launch(void* const* d_in, const int* in_sizes, int n_in,
                              void* d_out, int out_size, void* d_ws, size_t ws_size,
                              hipStream_t stream) {
    const float* x    = (const float*)d_in[0];
    const float* wgt  = (const float*)d_in[1];
    const float* bias = (const float*)d_in[2];
    float* out = (float*)d_out;

    dim3 grid(B_ * TILES_X_ * TILES_Y_);   // 16384 blocks
    conv3x3_min_tanh<<<grid, 256, 0, stream>>>(x, wgt, bias, out);
}

// Round 2
// 472.615 us; speedup vs baseline: 1.2927x; 1.2927x over previous
//
#include <hip/hip_runtime.h>

// Problem constants
#define B_  64
#define C_  3
#define H_  512
#define W_  512
#define OC_ 16
#define OH_ 510
#define OW_ 510

// Tile geometry: each 256-thread block computes a 64(x) x 16(y) output tile.
#define TX_ 64
#define TY_ 16
#define TILES_X_ 8    // ceil(510/64)
#define TILES_Y_ 32   // ceil(510/16)
#define SMW_ 66       // TX+2
#define SMH_ 18       // TY+2

// NaN-safe tanh: 1 - 2/(e^{2x}+1). For 2x overflow e=inf -> 1-0 = 1 (no inf/inf).
__device__ __forceinline__ float fast_tanh(float v) {
    float e = __expf(2.0f * v);
    return 1.0f - 2.0f * __builtin_amdgcn_rcpf(e + 1.0f);
}

__global__ __launch_bounds__(256, 4)
void conv3x3_min_tanh(const float* __restrict__ x, const float* __restrict__ wgt,
                      const float* __restrict__ bias, float* __restrict__ out) {
    __shared__ float smem[C_ * SMH_ * SMW_];   // 3*18*66*4 = 14.3 KB

    const int blk = blockIdx.x;
    const int bx = blk % TILES_X_;
    const int by = (blk / TILES_X_) % TILES_Y_;
    const int b  = blk / (TILES_X_ * TILES_Y_);
    const int ox0 = bx * TX_;
    const int oy0 = by * TY_;

    // ---- stage input tile (clamped at borders; clamped values never stored) ----
    const float* xb = x + (size_t)b * C_ * H_ * W_;
    constexpr int NSTAGE = C_ * SMH_ * SMW_;   // 3564
    for (int i = threadIdx.x; i < NSTAGE; i += 256) {
        int c  = i / (SMH_ * SMW_);
        int r  = (i % (SMH_ * SMW_)) / SMW_;
        int xx = i % SMW_;
        int gy = min(oy0 + r,  H_ - 1);
        int gx = min(ox0 + xx, W_ - 1);
        smem[i] = xb[(c * H_ + gy) * W_ + gx];
    }
    __syncthreads();

    // ---- compute: each thread owns x = ox0+lx, y = oy0 + tyg*4 + p (p=0..3) ----
    const int lx  = threadIdx.x & 63;
    const int tyg = threadIdx.x >> 6;   // 0..3

    // Load ALL 54 tap values into VGPRs once and PIN them so the compiler
    // cannot rematerialize LDS reads inside the o-loop (R1 failure mode:
    // VGPR=40 -> loop interchange -> 864 ds_reads/thread).
    float iv[C_][6][3];
    #pragma unroll
    for (int c = 0; c < C_; ++c)
        #pragma unroll
        for (int r = 0; r < 6; ++r)
            #pragma unroll
            for (int k = 0; k < 3; ++k) {
                float v = smem[(c * SMH_ + tyg * 4 + r) * SMW_ + lx + k];
                asm volatile("" : "+v"(v));   // pin in VGPR, forbid remat
                iv[c][r][k] = v;
            }

    float mn0 = 1e30f, mn1 = 1e30f, mn2 = 1e30f, mn3 = 1e30f;

    #pragma unroll
    for (int o = 0; o < OC_; ++o) {
        float bv = bias[o];                   // wave-uniform -> s_load
        float a0 = bv, a1 = bv, a2 = bv, a3 = bv;
        #pragma unroll
        for (int c = 0; c < C_; ++c)
            #pragma unroll
            for (int ky = 0; ky < 3; ++ky)
                #pragma unroll
                for (int kx = 0; kx < 3; ++kx) {
                    // wave-uniform weight -> SGPR operand of v_fma_f32
                    float wv = wgt[((o * C_ + c) * 3 + ky) * 3 + kx];
                    a0 = fmaf(wv, iv[c][0 + ky][kx], a0);
                    a1 = fmaf(wv, iv[c][1 + ky][kx], a1);
                    a2 = fmaf(wv, iv[c][2 + ky][kx], a2);
                    a3 = fmaf(wv, iv[c][3 + ky][kx], a3);
                }
        mn0 = fminf(mn0, a0);
        mn1 = fminf(mn1, a1);
        mn2 = fminf(mn2, a2);
        mn3 = fminf(mn3, a3);
    }

    // ---- epilogue: double tanh, coalesced store ----
    float mn[4] = {mn0, mn1, mn2, mn3};
    #pragma unroll
    for (int p = 0; p < 4; ++p) {
        float t = fast_tanh(fast_tanh(mn[p]));
        int oy = oy0 + tyg * 4 + p;
        int ox = ox0 + lx;
        if (oy < OH_ && ox < OW_)
            out[((size_t)b * OH_ + oy) * OW_ + ox] = t;
    }
}

extern "C" void kernel_launch(void* const* d_in, const int* in_sizes, int n_in,
                              void* d_out, int out_size, void* d_ws, size_t ws_size,
                              hipStream_t stream) {
    const float* x    = (const float*)d_in[0];
    const float* wgt  = (const float*)d_in[1];
    const float* bias = (const float*)d_in[2];
    float* out = (float*)d_out;

    dim3 grid(B_ * TILES_X_ * TILES_Y_);   // 16384 blocks
    conv3x3_min_tanh<<<grid, 256, 0, stream>>>(x, wgt, bias, out);
}

// Round 3
// 270.584 us; speedup vs baseline: 2.2579x; 1.7466x over previous
//
#include <hip/hip_runtime.h>

// Problem constants
#define B_  64
#define C_  3
#define H_  512
#define W_  512
#define OC_ 16
#define OH_ 510
#define OW_ 510

// Tile geometry: 512-thread block computes a 64(x) x 8(y) output tile, one
// output pixel per thread (P=1 keeps live set ~30 VGPR: 16 acc + 9 taps).
#define TX_ 64
#define TY_ 8
#define TILES_X_ 8    // ceil(510/64)
#define TILES_Y_ 64   // ceil(510/8)
#define SMW_ 66       // TX+2
#define SMH_ 10       // TY+2

// NaN-safe tanh: 1 - 2/(e^{2x}+1). For 2x overflow e=inf -> 1-0 = 1 (no inf/inf).
__device__ __forceinline__ float fast_tanh(float v) {
    float e = __expf(2.0f * v);
    return 1.0f - 2.0f * __builtin_amdgcn_rcpf(e + 1.0f);
}

__global__ __launch_bounds__(512, 4)
void conv3x3_min_tanh(const float* __restrict__ x, const float* __restrict__ wgt,
                      const float* __restrict__ bias, float* __restrict__ out) {
    __shared__ float smem[C_ * SMH_ * SMW_];   // 3*10*66*4 = 7.9 KB

    const int blk = blockIdx.x;
    const int bx = blk % TILES_X_;
    const int by = (blk / TILES_X_) % TILES_Y_;
    const int b  = blk / (TILES_X_ * TILES_Y_);
    const int ox0 = bx * TX_;
    const int oy0 = by * TY_;

    // ---- stage input tile (border-clamped; clamped values never stored) ----
    const float* xb = x + (size_t)b * C_ * H_ * W_;
    constexpr int NSTAGE = C_ * SMH_ * SMW_;   // 1980
    for (int i = threadIdx.x; i < NSTAGE; i += 512) {
        int c  = i / (SMH_ * SMW_);
        int r  = (i % (SMH_ * SMW_)) / SMW_;
        int xx = i % SMW_;
        int gy = min(oy0 + r,  H_ - 1);
        int gx = min(ox0 + xx, W_ - 1);
        smem[i] = xb[(c * H_ + gy) * W_ + gx];
    }
    __syncthreads();

    // ---- compute: thread -> output (ox0+lx, oy0+ty) ----
    const int lx = threadIdx.x & 63;
    const int ty = threadIdx.x >> 6;   // 0..7

    float acc[OC_];
    #pragma unroll
    for (int o = 0; o < OC_; ++o) acc[o] = bias[o];   // wave-uniform s_load

    #pragma unroll
    for (int c = 0; c < C_; ++c) {
        // 9 taps for this channel; pin so they stay in VGPRs across the o-loop
        float tp[3][3];
        #pragma unroll
        for (int dy = 0; dy < 3; ++dy)
            #pragma unroll
            for (int dx = 0; dx < 3; ++dx) {
                float v = smem[(c * SMH_ + ty + dy) * SMW_ + lx + dx];
                asm volatile("" : "+v"(v));
                tp[dy][dx] = v;
            }

        #pragma unroll
        for (int o = 0; o < OC_; ++o)
            #pragma unroll
            for (int dy = 0; dy < 3; ++dy)
                #pragma unroll
                for (int dx = 0; dx < 3; ++dx) {
                    // wave-uniform weight -> SGPR operand of v_fma_f32
                    float wv = wgt[((o * C_ + c) * 3 + dy) * 3 + dx];
                    acc[o] = fmaf(wv, tp[dy][dx], acc[o]);
                }
    }

    // ---- epilogue: channel-min, double tanh, coalesced store ----
    float m = acc[0];
    #pragma unroll
    for (int o = 1; o < OC_; ++o) m = fminf(m, acc[o]);
    float t = fast_tanh(fast_tanh(m));

    int oy = oy0 + ty;
    int ox = ox0 + lx;
    if (oy < OH_ && ox < OW_)
        out[((size_t)b * OH_ + oy) * OW_ + ox] = t;
}

extern "C" void kernel_launch(void* const* d_in, const int* in_sizes, int n_in,
                              void* d_out, int out_size, void* d_ws, size_t ws_size,
                              hipStream_t stream) {
    const float* x    = (const float*)d_in[0];
    const float* wgt  = (const float*)d_in[1];
    const float* bias = (const float*)d_in[2];
    float* out = (float*)d_out;

    dim3 grid(B_ * TILES_X_ * TILES_Y_);   // 32768 blocks
    conv3x3_min_tanh<<<grid, 512, 0, stream>>>(x, wgt, bias, out);
}

// Round 4
// 259.499 us; speedup vs baseline: 2.3544x; 1.0427x over previous
//
#include <hip/hip_runtime.h>
#include <stdint.h>

// Problem constants
#define B_  64
#define C_  3
#define H_  512
#define W_  512
#define OC_ 16
#define OH_ 510
#define OW_ 510

// Tile geometry: 512-thread block computes a 64(x) x 8(y) output tile,
// one output pixel per thread.
#define TX_ 64
#define TY_ 8
#define TILES_X_ 8    // ceil(510/64)
#define TILES_Y_ 64   // ceil(510/8)
#define SMW_ 66       // TX+2
#define SMH_ 10       // TY+2

// NaN-safe tanh: 1 - 2/(e^{2x}+1). For 2x overflow e=inf -> 1-0 = 1 (no inf/inf).
__device__ __forceinline__ float fast_tanh(float v) {
    float e = __expf(2.0f * v);
    return 1.0f - 2.0f * __builtin_amdgcn_rcpf(e + 1.0f);
}

__global__ __launch_bounds__(512, 4)
void conv3x3_min_tanh(const float* __restrict__ x, const float* __restrict__ wgt,
                      const float* __restrict__ bias, float* __restrict__ out) {
    __shared__ float smem[C_ * SMH_ * SMW_];   // 3*10*66*4 = 7.9 KB

    const int blk = blockIdx.x;
    const int bx = blk % TILES_X_;
    const int by = (blk / TILES_X_) % TILES_Y_;
    const int b  = blk / (TILES_X_ * TILES_Y_);
    const int ox0 = bx * TX_;
    const int oy0 = by * TY_;

    // ---- stage input tile (border-clamped; clamped values never stored) ----
    const float* xb = x + (size_t)b * C_ * H_ * W_;
    constexpr int NSTAGE = C_ * SMH_ * SMW_;   // 1980
    for (int i = threadIdx.x; i < NSTAGE; i += 512) {
        int c  = i / (SMH_ * SMW_);
        int r  = (i % (SMH_ * SMW_)) / SMW_;
        int xx = i % SMW_;
        int gy = min(oy0 + r,  H_ - 1);
        int gx = min(ox0 + xx, W_ - 1);
        smem[i] = xb[(c * H_ + gy) * W_ + gx];
    }
    __syncthreads();

    // ---- compute: thread -> output (ox0+lx, oy0+ty) ----
    const int lx = threadIdx.x & 63;
    const int ty = threadIdx.x >> 6;   // 0..7

    // Load all 27 taps ONCE via inline-asm ds_read_b32. The values are born
    // as opaque asm outputs -> no IR load exists for the compiler to
    // rematerialize inside the o-loop (R2/R3 failure mode: o-outer remat,
    // 432 ds_reads/thread, LDS-issue-bound at ~265us).
    // Shared aperture is 4GB-aligned -> low 32 bits of generic ptr = LDS offset.
    const uint32_t lds_base = (uint32_t)(uintptr_t)(&smem[0]);
    float tap[27];
    #pragma unroll
    for (int c = 0; c < C_; ++c)
        #pragma unroll
        for (int dy = 0; dy < 3; ++dy)
            #pragma unroll
            for (int dx = 0; dx < 3; ++dx) {
                uint32_t addr = lds_base +
                    4u * (uint32_t)((c * SMH_ + ty + dy) * SMW_ + lx + dx);
                asm volatile("ds_read_b32 %0, %1"
                             : "=v"(tap[(c * 3 + dy) * 3 + dx])
                             : "v"(addr));
            }
    asm volatile("s_waitcnt lgkmcnt(0)" ::: "memory");
    __builtin_amdgcn_sched_barrier(0);   // rule #18: don't let FMAs hoist past wait

    // o-outer with running min (taps stay resident); 2 channels in flight
    // for FMA-latency ILP (2 indep chains saturate wave issue).
    float mn = __builtin_inff();
    #pragma unroll
    for (int o = 0; o < OC_; o += 2) {
        float a0 = bias[o];
        float a1 = bias[o + 1];
        #pragma unroll
        for (int t = 0; t < 27; ++t) {
            // wave-uniform weights -> SGPR operand of v_fma_f32
            a0 = fmaf(wgt[o * 27 + t],       tap[t], a0);
            a1 = fmaf(wgt[(o + 1) * 27 + t], tap[t], a1);
        }
        mn = fminf(mn, fminf(a0, a1));
    }

    // ---- epilogue: double tanh, coalesced store ----
    float t = fast_tanh(fast_tanh(mn));
    int oy = oy0 + ty;
    int ox = ox0 + lx;
    if (oy < OH_ && ox < OW_)
        out[((size_t)b * OH_ + oy) * OW_ + ox] = t;
}

extern "C" void kernel_launch(void* const* d_in, const int* in_sizes, int n_in,
                              void* d_out, int out_size, void* d_ws, size_t ws_size,
                              hipStream_t stream) {
    const float* x    = (const float*)d_in[0];
    const float* wgt  = (const float*)d_in[1];
    const float* bias = (const float*)d_in[2];
    float* out = (float*)d_out;

    dim3 grid(B_ * TILES_X_ * TILES_Y_);   // 32768 blocks
    conv3x3_min_tanh<<<grid, 512, 0, stream>>>(x, wgt, bias, out);
}